// Round 9
// baseline (1047.891 us; speedup 1.0000x reference)
//
#include <hip/hip_runtime.h>
#include <hip/hip_fp16.h>

#define NN   100000     // nodes
#define NE   1600000    // edges
#define INF_ 128        // input features
#define HD   32         // hidden = HEADS*HEAD_D
#define TT   3          // edge types
#define LL   2          // layers
#define NBLK ((NN + 255) / 256)

// binning sort parameters
#define BSH   9                      // 512 nodes per bucket
#define NBUK  ((NN + 511) / 512)     // 196 buckets
#define BCAP  12288                  // slots per bucket (mean 8163, huge margin)
#define CHUNK 4096                   // edges per bin_edges block
#define EPT   16                     // edges per thread
#define NCHNK ((NE + CHUNK - 1) / CHUNK)  // 391
#define NSEG  (512 * TT)             // 1536 segments per bucket

// agg kernel
#define AGGN    128                  // dst nodes per agg block
#define ASTRIDE 104                  // floats per node in LDS: u[3][32] + den @96, pad
#define NAGG    ((NN + AGGN - 1) / AGGN)   // 782

static const float RSQRT_D = 0.17677669529663687f;  // 1/sqrt(32)

// h = x @ in_W + in_b   (block: 8 nodes x 32 dims)
__global__ void input_proj(const float* __restrict__ x,
                           const float* __restrict__ inW,
                           const float* __restrict__ inb,
                           float* __restrict__ h) {
    __shared__ float sW[INF_ * HD];   // 16 KB
    __shared__ float sx[8 * INF_];    // 4 KB
    for (int i = threadIdx.x; i < INF_ * HD; i += 256) sW[i] = inW[i];
    int node0 = blockIdx.x * 8;
    {
        const float4* xs = (const float4*)(x + (size_t)node0 * INF_);
        float4* dst4 = (float4*)sx;
        dst4[threadIdx.x] = xs[threadIdx.x];
    }
    __syncthreads();
    int ln = threadIdx.x / HD, d = threadIdx.x % HD;
    int n = node0 + ln;
    float acc = inb[d];
    #pragma unroll
    for (int i = 0; i < INF_; ++i) acc += sx[ln * INF_ + i] * sW[i * HD + d];
    h[(size_t)n * HD + d] = acc;
}

// ---------------- CSR build: LDS-staged two-pass binning ----------------
__global__ void zero_cursor(int* __restrict__ cursor) {
    if (threadIdx.x < NBUK) cursor[threadIdx.x] = 0;
}

// pass A: bin edges by dst>>9; chunk-local LDS reorder, near-coalesced writes
__global__ void bin_edges(const int* __restrict__ src, const int* __restrict__ dst,
                          const int* __restrict__ etype,
                          unsigned* __restrict__ bin, int* __restrict__ cursor) {
    __shared__ int hist[256];
    __shared__ int scn[256];
    __shared__ int gofs[256];
    __shared__ int fillc[256];
    __shared__ unsigned buf[CHUNK];
    __shared__ unsigned short bufb[CHUNK];
    int tid = threadIdx.x;
    int e0 = blockIdx.x * CHUNK;
    unsigned ent[EPT];
    int bkt[EPT];
    hist[tid] = 0;
    fillc[tid] = 0;
    __syncthreads();
    #pragma unroll
    for (int j = 0; j < EPT; ++j) {
        int e = e0 + j * 256 + tid;
        if (e < NE) {
            int dn = dst[e];
            int b = dn >> BSH;
            ent[j] = ((unsigned)src[e] << 11) | ((unsigned)(dn & 511) << 2)
                   | (unsigned)etype[e];
            bkt[j] = b;
            atomicAdd(&hist[b], 1);
        } else bkt[j] = -1;
    }
    __syncthreads();
    int v = hist[tid];
    scn[tid] = v;
    __syncthreads();
    for (int off = 1; off < 256; off <<= 1) {
        int t = (tid >= off) ? scn[tid - off] : 0;
        __syncthreads();
        scn[tid] += t;
        __syncthreads();
    }
    int excl = scn[tid] - v;
    int total = scn[255];
    if (v > 0) gofs[tid] = atomicAdd(&cursor[tid], v);
    hist[tid] = excl;
    __syncthreads();
    #pragma unroll
    for (int j = 0; j < EPT; ++j) {
        if (bkt[j] >= 0) {
            int r = atomicAdd(&fillc[bkt[j]], 1);
            int pos = hist[bkt[j]] + r;
            buf[pos] = ent[j];
            bufb[pos] = (unsigned short)bkt[j];
        }
    }
    __syncthreads();
    for (int pos = tid; pos < total; pos += 256) {
        int b = bufb[pos];
        int g = gofs[b] + (pos - hist[b]);
        bin[(size_t)b * BCAP + g] = buf[pos];
    }
}

// exclusive scan over NBUK bucket totals
__global__ void scan_buckets(const int* __restrict__ cursor, int* __restrict__ bbase) {
    __shared__ int s[256];
    int tid = threadIdx.x;
    int v = (tid < NBUK) ? cursor[tid] : 0;
    s[tid] = v;
    __syncthreads();
    for (int off = 1; off < 256; off <<= 1) {
        int t = (tid >= off) ? s[tid - off] : 0;
        __syncthreads();
        s[tid] += t;
        __syncthreads();
    }
    if (tid < NBUK) bbase[tid] = s[tid] - v;
}

// pass B: per-bucket segment hist + scan + rowptr + placement (einfo, dcsr)
__global__ void build_bucket(const unsigned* __restrict__ bin, const int* __restrict__ cursor,
                             const int* __restrict__ bbase, int* __restrict__ rowptr,
                             int* __restrict__ einfo, int* __restrict__ dcsr) {
    __shared__ int hist[NSEG];
    __shared__ int fill2[NSEG];
    __shared__ int tsum[256];
    int b = blockIdx.x, tid = threadIdx.x;
    int cnt = cursor[b], base = bbase[b];
    const unsigned* eb = bin + (size_t)b * BCAP;
    for (int j = tid; j < NSEG; j += 256) { hist[j] = 0; fill2[j] = 0; }
    __syncthreads();
    for (int i = tid; i < cnt; i += 256) {
        unsigned u = eb[i];
        atomicAdd(&hist[((u >> 2) & 511) * TT + (u & 3)], 1);
    }
    __syncthreads();
    int b6 = tid * 6;
    int s = 0;
    #pragma unroll
    for (int j = 0; j < 6; ++j) s += hist[b6 + j];
    tsum[tid] = s;
    __syncthreads();
    for (int off = 1; off < 256; off <<= 1) {
        int t = (tid >= off) ? tsum[tid - off] : 0;
        __syncthreads();
        tsum[tid] += t;
        __syncthreads();
    }
    int run = tsum[tid] - s;
    #pragma unroll
    for (int j = 0; j < 6; ++j) { int c = hist[b6 + j]; hist[b6 + j] = run; run += c; }
    __syncthreads();
    for (int j = tid; j < NSEG; j += 256) rowptr[b * NSEG + j] = base + hist[j];
    for (int i = tid; i < cnt; i += 256) {
        unsigned u = eb[i];
        int t = u & 3, dl = (u >> 2) & 511, sn = u >> 11;
        int seg = dl * TT + t;
        int p = base + hist[seg] + atomicAdd(&fill2[seg], 1);
        einfo[p] = (sn << 2) | t;
        dcsr[p] = (b << BSH) + dl;
    }
}

// ---------------- per-layer kernels ----------------

// WqR[t] = Wq_l @ Ratt_t^T * pri_t / sqrt(d);  RW[t] = Rmsg_t @ Wa_l
__global__ void combine_mats2(const float* __restrict__ Wq, const float* __restrict__ Ratt,
                              const float* __restrict__ Rmsg, const float* __restrict__ Wa,
                              const float* __restrict__ pri,
                              float* __restrict__ WqR, float* __restrict__ RW, int layer) {
    int idx = blockIdx.x * blockDim.x + threadIdx.x;   // 6144
    if (idx >= 2 * TT * HD * HD) return;
    int which = idx / (TT * HD * HD);
    int rr = idx % (TT * HD * HD);
    int t = rr / (HD * HD);
    int ij = rr % (HD * HD);
    int i = ij / HD, j = ij % HD;
    if (which == 0) {
        const float* wq = Wq + layer * HD * HD;
        const float* ra = Ratt + (size_t)(layer * TT + t) * HD * HD;
        float acc = 0.f;
        #pragma unroll
        for (int e = 0; e < HD; ++e) acc += wq[i * HD + e] * ra[j * HD + e];
        WqR[t * HD * HD + ij] = acc * pri[layer * TT + t] * RSQRT_D;
    } else {
        const float* rm = Rmsg + (size_t)(layer * TT + t) * HD * HD;
        const float* wa = Wa + layer * HD * HD;
        float acc = 0.f;
        #pragma unroll
        for (int e = 0; e < HD; ++e) acc += rm[i * HD + e] * wa[e * HD + j];
        RW[t * HD * HD + ij] = acc;
    }
}

// per node: k = h@Wk ; v = h@Wv ; q_rel[t] = h@WqR[t]  (k,v,q_rel stored fp16)
__global__ void node_proj6(const float* __restrict__ h, const float* __restrict__ Wk,
                           const float* __restrict__ Wv, const float* __restrict__ WqR,
                           __half* __restrict__ k16, __half* __restrict__ v16,
                           __half* __restrict__ q16, int layer) {
    __shared__ float sK[HD * HD];
    __shared__ float sV[HD * HD];
    __shared__ float sQ[TT * HD * HD];
    __shared__ float sh[8 * HD];
    const float* wk = Wk + layer * HD * HD;
    const float* wv = Wv + layer * HD * HD;
    for (int i = threadIdx.x; i < HD * HD; i += 256) { sK[i] = wk[i]; sV[i] = wv[i]; }
    for (int i = threadIdx.x; i < TT * HD * HD; i += 256) sQ[i] = WqR[i];
    int node0 = blockIdx.x * 8;
    {
        const float4* hs = (const float4*)(h + (size_t)node0 * HD);
        float4* dst4 = (float4*)sh;
        if (threadIdx.x < 64) dst4[threadIdx.x] = hs[threadIdx.x];
    }
    __syncthreads();
    int ln = threadIdx.x / HD, d = threadIdx.x % HD;
    int n = node0 + ln;
    float ak = 0.f, av = 0.f, a0 = 0.f, a1 = 0.f, a2 = 0.f;
    #pragma unroll
    for (int i = 0; i < HD; ++i) {
        float hv = sh[ln * HD + i];
        ak += hv * sK[i * HD + d];
        av += hv * sV[i * HD + d];
        a0 += hv * sQ[0 * HD * HD + i * HD + d];
        a1 += hv * sQ[1 * HD * HD + i * HD + d];
        a2 += hv * sQ[2 * HD * HD + i * HD + d];
    }
    k16[(size_t)n * HD + d] = __float2half(ak);
    v16[(size_t)n * HD + d] = __float2half(av);
    q16[(0 * (size_t)NN + n) * HD + d] = __float2half(a0);
    q16[(1 * (size_t)NN + n) * HD + d] = __float2half(a1);
    q16[(2 * (size_t)NN + n) * HD + d] = __float2half(a2);
}

__device__ __forceinline__ float dot4_h(float2 kraw, float2 qraw) {
    __half2 k01 = *(__half2*)&kraw.x, k23 = *(__half2*)&kraw.y;
    __half2 q01 = *(__half2*)&qraw.x, q23 = *(__half2*)&qraw.y;
    float2 a = __half22float2(k01), b = __half22float2(q01);
    float2 c = __half22float2(k23), e = __half22float2(q23);
    return a.x * b.x + a.y * b.y + c.x * e.x + c.y * e.y;
}

// logits in CSR slot order; payload {x=exp(a), packed (dl7<<25)|(src<<2)|t}.
// Shift-0 softmax is exact here: |logit| <= ~0.5 given 0.05-scaled weights.
__global__ void edge_logits_exp(const int* __restrict__ einfo, const int* __restrict__ dcsr,
                                const __half* __restrict__ k16, const __half* __restrict__ q16,
                                float2* __restrict__ pay) {
    int p = blockIdx.x * 32 + (threadIdx.x >> 3);
    if (p >= NE) return;
    int g = threadIdx.x & 7;
    int sid = einfo[p];
    unsigned srcn = ((unsigned)sid) >> 2, t = (unsigned)sid & 3;
    int dn = dcsr[p];
    float2 kraw = ((const float2*)k16)[(size_t)srcn * 8 + g];
    float2 qraw = ((const float2*)q16)[((size_t)t * NN + dn) * 8 + g];
    float acc = dot4_h(kraw, qraw);
    acc += __shfl_xor(acc, 1);
    acc += __shfl_xor(acc, 2);
    acc += __shfl_xor(acc, 4);
    if (g == 0) {
        unsigned y = ((unsigned)(dn & (AGGN - 1)) << 25) | (srcn << 2) | t;
        pay[p] = make_float2(__expf(acc), __uint_as_float(y));
    }
}

// edge-parallel aggregation: block owns 128 dst nodes; LDS atomic accumulation
// of u[3][32]+den per node, then fused (Rmsg_t@Wa) + gate + relu from LDS.
__global__ __launch_bounds__(512) void bucket_agg(
        const int* __restrict__ rowptr, const float2* __restrict__ pay,
        const __half* __restrict__ v16, const float* __restrict__ RW,
        const float* __restrict__ skip, float* __restrict__ h, int layer) {
    __shared__ float sacc[AGGN * ASTRIDE];   // 52 KB
    __shared__ float sRW[TT * HD * HD];      // 12 KB
    int tid = threadIdx.x;
    for (int i = tid; i < AGGN * ASTRIDE; i += 512) sacc[i] = 0.f;
    for (int i = tid; i < TT * HD * HD; i += 512) sRW[i] = RW[i];
    int n0 = blockIdx.x * AGGN;
    int nE = n0 + AGGN;                       // 128-aligned; stays within rowptr range
    int s0 = rowptr[(n0 >> BSH) * NSEG + (n0 & 511) * TT];
    int s1 = rowptr[(nE >> BSH) * NSEG + (nE & 511) * TT];
    __syncthreads();
    int sub = tid >> 3, g = tid & 7;          // 64 subgroups of 8 lanes
    for (int p = s0 + sub; p < s1; p += 64) {
        float2 pp = pay[p];
        unsigned y = __float_as_uint(pp.y);
        float x = pp.x;
        float2 vr = ((const float2*)v16)[(size_t)((y >> 2) & 0x1FFFFu) * 8 + g];
        __half2 h01 = *(__half2*)&vr.x, h23 = *(__half2*)&vr.y;
        float2 f01 = __half22float2(h01), f23 = __half22float2(h23);
        float* base = &sacc[(y >> 25) * ASTRIDE + (y & 3) * HD + g * 4];
        atomicAdd(base + 0, x * f01.x);
        atomicAdd(base + 1, x * f01.y);
        atomicAdd(base + 2, x * f23.x);
        atomicAdd(base + 3, x * f23.y);
        if (g == 0) atomicAdd(&sacc[(y >> 25) * ASTRIDE + 96], x);
    }
    __syncthreads();
    float gate = 1.f / (1.f + __expf(-skip[layer]));
    for (int i = tid; i < AGGN * HD; i += 512) {
        int nl = i >> 5, d = i & 31;
        int n = n0 + nl;
        if (n >= NN) break;
        float den = sacc[nl * ASTRIDE + 96];
        float inv = (den > 0.f) ? 1.f / den : 0.f;
        float o = 0.f;
        #pragma unroll
        for (int t = 0; t < TT; ++t) {
            const float* u = &sacc[nl * ASTRIDE + t * HD];
            const float* w = &sRW[t * HD * HD];
            #pragma unroll
            for (int j = 0; j < HD; ++j) o += u[j] * w[j * HD + d];
        }
        o *= inv;
        size_t idx = (size_t)n * HD + d;
        float val = o * gate + h[idx] * (1.f - gate);
        h[idx] = fmaxf(val, 0.f);
    }
}

// out = h @ mlp_W + mlp_b  (C=2)
__global__ void mlp_out(const float* __restrict__ h, const float* __restrict__ W,
                        const float* __restrict__ b, float* __restrict__ out) {
    int n = blockIdx.x * blockDim.x + threadIdx.x;
    if (n >= NN) return;
    const float4* hr = (const float4*)(h + (size_t)n * HD);
    float acc0 = b[0], acc1 = b[1];
    #pragma unroll
    for (int j = 0; j < HD / 4; ++j) {
        float4 hv = hr[j];
        acc0 += hv.x * W[(4 * j + 0) * 2 + 0] + hv.y * W[(4 * j + 1) * 2 + 0]
              + hv.z * W[(4 * j + 2) * 2 + 0] + hv.w * W[(4 * j + 3) * 2 + 0];
        acc1 += hv.x * W[(4 * j + 0) * 2 + 1] + hv.y * W[(4 * j + 1) * 2 + 1]
              + hv.z * W[(4 * j + 2) * 2 + 1] + hv.w * W[(4 * j + 3) * 2 + 1];
    }
    out[(size_t)n * 2 + 0] = acc0;
    out[(size_t)n * 2 + 1] = acc1;
}

extern "C" void kernel_launch(void* const* d_in, const int* in_sizes, int n_in,
                              void* d_out, int out_size, void* d_ws, size_t ws_size,
                              hipStream_t stream) {
    const float* x     = (const float*)d_in[0];
    const int*   src   = (const int*)d_in[1];
    const int*   dst   = (const int*)d_in[2];
    const int*   etype = (const int*)d_in[3];
    const float* in_W  = (const float*)d_in[4];
    const float* in_b  = (const float*)d_in[5];
    const float* Wk    = (const float*)d_in[6];
    const float* Wq    = (const float*)d_in[7];
    const float* Wv    = (const float*)d_in[8];
    const float* Wa    = (const float*)d_in[9];
    const float* pri   = (const float*)d_in[10];
    const float* Ratt  = (const float*)d_in[11];
    const float* Rmsg  = (const float*)d_in[12];
    const float* skip  = (const float*)d_in[13];
    const float* mlp_W = (const float*)d_in[14];
    const float* mlp_b = (const float*)d_in[15];
    float* out = (float*)d_out;

    float* ws = (float*)d_ws;
    float*  h     = ws;                            // NN*HD f32
    float2* pay   = (float2*)(h + (size_t)NN * HD);// NE float2
    float*  WqR   = (float*)(pay + NE);            // 3*HD*HD f32
    float*  RW    = WqR + TT * HD * HD;            // 3*HD*HD f32
    __half* k16   = (__half*)(RW + TT * HD * HD);  // NN*HD halves
    __half* v16   = k16 + (size_t)NN * HD;         // NN*HD halves
    __half* q16   = v16 + (size_t)NN * HD;         // 3*NN*HD halves
    int* rowptr   = (int*)(q16 + (size_t)3 * NN * HD);  // NBUK*NSEG + 1
    int* cursor   = rowptr + NBUK * NSEG + 1;      // 256
    int* bbase    = cursor + 256;                  // 256
    int* einfo    = bbase + 256;                   // NE
    int* dcsr     = einfo + NE;                    // NE
    unsigned* bin = (unsigned*)(dcsr + NE);        // NBUK*BCAP

    input_proj<<<NN / 8, 256, 0, stream>>>(x, in_W, in_b, h);

    zero_cursor<<<1, 256, 0, stream>>>(cursor);
    bin_edges<<<NCHNK, 256, 0, stream>>>(src, dst, etype, bin, cursor);
    scan_buckets<<<1, 256, 0, stream>>>(cursor, bbase);
    build_bucket<<<NBUK, 256, 0, stream>>>(bin, cursor, bbase, rowptr, einfo, dcsr);

    for (int l = 0; l < LL; ++l) {
        combine_mats2<<<(2 * TT * HD * HD + 255) / 256, 256, 0, stream>>>(
            Wq, Ratt, Rmsg, Wa, pri, WqR, RW, l);
        node_proj6<<<NN / 8, 256, 0, stream>>>(h, Wk, Wv, WqR, k16, v16, q16, l);
        edge_logits_exp<<<(NE + 31) / 32, 256, 0, stream>>>(einfo, dcsr, k16, q16, pay);
        bucket_agg<<<NAGG, 512, 0, stream>>>(rowptr, pay, v16, RW, skip, h, l);
    }
    mlp_out<<<(NN + 255) / 256, 256, 0, stream>>>(h, mlp_W, mlp_b, out);
}

// Round 10
// 438.423 us; speedup vs baseline: 2.3901x; 2.3901x over previous
//
#include <hip/hip_runtime.h>
#include <hip/hip_fp16.h>

#define NN   100000     // nodes
#define NE   1600000    // edges
#define INF_ 128        // input features
#define HD   32         // hidden = HEADS*HEAD_D
#define TT   3          // edge types
#define LL   2          // layers
#define NBLK ((NN + 255) / 256)

// binning sort parameters
#define BSH   9                      // 512 nodes per bucket
#define NBUK  ((NN + 511) / 512)     // 196 buckets
#define BCAP  12288                  // slots per bucket (mean 8163, huge margin)
#define CHUNK 4096                   // edges per bin_edges block
#define EPT   16                     // edges per thread
#define NCHNK ((NE + CHUNK - 1) / CHUNK)  // 391
#define NSEG  (512 * TT)             // 1536 segments per bucket

static const float RSQRT_D = 0.17677669529663687f;  // 1/sqrt(32)

// h = x @ in_W + in_b   (block: 8 nodes x 32 dims)
__global__ void input_proj(const float* __restrict__ x,
                           const float* __restrict__ inW,
                           const float* __restrict__ inb,
                           float* __restrict__ h) {
    __shared__ float sW[INF_ * HD];   // 16 KB
    __shared__ float sx[8 * INF_];    // 4 KB
    for (int i = threadIdx.x; i < INF_ * HD; i += 256) sW[i] = inW[i];
    int node0 = blockIdx.x * 8;
    {
        const float4* xs = (const float4*)(x + (size_t)node0 * INF_);
        float4* dst4 = (float4*)sx;
        dst4[threadIdx.x] = xs[threadIdx.x];
    }
    __syncthreads();
    int ln = threadIdx.x / HD, d = threadIdx.x % HD;
    int n = node0 + ln;
    float acc = inb[d];
    #pragma unroll
    for (int i = 0; i < INF_; ++i) acc += sx[ln * INF_ + i] * sW[i * HD + d];
    h[(size_t)n * HD + d] = acc;
}

// ---------------- CSR build: LDS-staged two-pass binning ----------------
__global__ void zero_cursor(int* __restrict__ cursor) {
    if (threadIdx.x < NBUK) cursor[threadIdx.x] = 0;
}

// pass A: bin edges by dst>>9; chunk-local LDS reorder, near-coalesced writes
__global__ void bin_edges(const int* __restrict__ src, const int* __restrict__ dst,
                          const int* __restrict__ etype,
                          unsigned* __restrict__ bin, int* __restrict__ cursor) {
    __shared__ int hist[256];
    __shared__ int scn[256];
    __shared__ int gofs[256];
    __shared__ int fillc[256];
    __shared__ unsigned buf[CHUNK];
    __shared__ unsigned short bufb[CHUNK];
    int tid = threadIdx.x;
    int e0 = blockIdx.x * CHUNK;
    unsigned ent[EPT];
    int bkt[EPT];
    hist[tid] = 0;
    fillc[tid] = 0;
    __syncthreads();
    #pragma unroll
    for (int j = 0; j < EPT; ++j) {
        int e = e0 + j * 256 + tid;
        if (e < NE) {
            int dn = dst[e];
            int b = dn >> BSH;
            ent[j] = ((unsigned)src[e] << 11) | ((unsigned)(dn & 511) << 2)
                   | (unsigned)etype[e];
            bkt[j] = b;
            atomicAdd(&hist[b], 1);
        } else bkt[j] = -1;
    }
    __syncthreads();
    int v = hist[tid];
    scn[tid] = v;
    __syncthreads();
    for (int off = 1; off < 256; off <<= 1) {
        int t = (tid >= off) ? scn[tid - off] : 0;
        __syncthreads();
        scn[tid] += t;
        __syncthreads();
    }
    int excl = scn[tid] - v;
    int total = scn[255];
    if (v > 0) gofs[tid] = atomicAdd(&cursor[tid], v);
    hist[tid] = excl;
    __syncthreads();
    #pragma unroll
    for (int j = 0; j < EPT; ++j) {
        if (bkt[j] >= 0) {
            int r = atomicAdd(&fillc[bkt[j]], 1);
            int pos = hist[bkt[j]] + r;
            buf[pos] = ent[j];
            bufb[pos] = (unsigned short)bkt[j];
        }
    }
    __syncthreads();
    for (int pos = tid; pos < total; pos += 256) {
        int b = bufb[pos];
        int g = gofs[b] + (pos - hist[b]);
        bin[(size_t)b * BCAP + g] = buf[pos];
    }
}

// exclusive scan over NBUK bucket totals
__global__ void scan_buckets(const int* __restrict__ cursor, int* __restrict__ bbase) {
    __shared__ int s[256];
    int tid = threadIdx.x;
    int v = (tid < NBUK) ? cursor[tid] : 0;
    s[tid] = v;
    __syncthreads();
    for (int off = 1; off < 256; off <<= 1) {
        int t = (tid >= off) ? s[tid - off] : 0;
        __syncthreads();
        s[tid] += t;
        __syncthreads();
    }
    if (tid < NBUK) bbase[tid] = s[tid] - v;
}

// pass B: per-bucket segment hist + scan + rowptr + placement (einfo, dcsr)
__global__ void build_bucket(const unsigned* __restrict__ bin, const int* __restrict__ cursor,
                             const int* __restrict__ bbase, int* __restrict__ rowptr,
                             int* __restrict__ einfo, int* __restrict__ dcsr) {
    __shared__ int hist[NSEG];
    __shared__ int fill2[NSEG];
    __shared__ int tsum[256];
    int b = blockIdx.x, tid = threadIdx.x;
    int cnt = cursor[b], base = bbase[b];
    const unsigned* eb = bin + (size_t)b * BCAP;
    for (int j = tid; j < NSEG; j += 256) { hist[j] = 0; fill2[j] = 0; }
    __syncthreads();
    for (int i = tid; i < cnt; i += 256) {
        unsigned u = eb[i];
        atomicAdd(&hist[((u >> 2) & 511) * TT + (u & 3)], 1);
    }
    __syncthreads();
    int b6 = tid * 6;
    int s = 0;
    #pragma unroll
    for (int j = 0; j < 6; ++j) s += hist[b6 + j];
    tsum[tid] = s;
    __syncthreads();
    for (int off = 1; off < 256; off <<= 1) {
        int t = (tid >= off) ? tsum[tid - off] : 0;
        __syncthreads();
        tsum[tid] += t;
        __syncthreads();
    }
    int run = tsum[tid] - s;
    #pragma unroll
    for (int j = 0; j < 6; ++j) { int c = hist[b6 + j]; hist[b6 + j] = run; run += c; }
    __syncthreads();
    for (int j = tid; j < NSEG; j += 256) rowptr[b * NSEG + j] = base + hist[j];
    for (int i = tid; i < cnt; i += 256) {
        unsigned u = eb[i];
        int t = u & 3, dl = (u >> 2) & 511, sn = u >> 11;
        int seg = dl * TT + t;
        int p = base + hist[seg] + atomicAdd(&fill2[seg], 1);
        einfo[p] = (sn << 2) | t;
        dcsr[p] = (b << BSH) + dl;
    }
}

// ---------------- per-layer kernels ----------------

// WqR[t] = Wq_l @ Ratt_t^T * pri_t / sqrt(d);  RW[t] = Rmsg_t @ Wa_l
__global__ void combine_mats2(const float* __restrict__ Wq, const float* __restrict__ Ratt,
                              const float* __restrict__ Rmsg, const float* __restrict__ Wa,
                              const float* __restrict__ pri,
                              float* __restrict__ WqR, float* __restrict__ RW, int layer) {
    int idx = blockIdx.x * blockDim.x + threadIdx.x;   // 6144
    if (idx >= 2 * TT * HD * HD) return;
    int which = idx / (TT * HD * HD);
    int rr = idx % (TT * HD * HD);
    int t = rr / (HD * HD);
    int ij = rr % (HD * HD);
    int i = ij / HD, j = ij % HD;
    if (which == 0) {
        const float* wq = Wq + layer * HD * HD;
        const float* ra = Ratt + (size_t)(layer * TT + t) * HD * HD;
        float acc = 0.f;
        #pragma unroll
        for (int e = 0; e < HD; ++e) acc += wq[i * HD + e] * ra[j * HD + e];
        WqR[t * HD * HD + ij] = acc * pri[layer * TT + t] * RSQRT_D;
    } else {
        const float* rm = Rmsg + (size_t)(layer * TT + t) * HD * HD;
        const float* wa = Wa + layer * HD * HD;
        float acc = 0.f;
        #pragma unroll
        for (int e = 0; e < HD; ++e) acc += rm[i * HD + e] * wa[e * HD + j];
        RW[t * HD * HD + ij] = acc;
    }
}

// per node: k = h@Wk ; q_rel[t] = h@WqR[t] ; v_rw[t] = (h@Wv)@RW[t]  (fp16 out)
__global__ void node_proj7(const float* __restrict__ h, const float* __restrict__ Wk,
                           const float* __restrict__ Wv, const float* __restrict__ WqR,
                           const float* __restrict__ RW,
                           __half* __restrict__ k16, __half* __restrict__ q16,
                           __half* __restrict__ vrw16, int layer) {
    __shared__ float sK[HD * HD];         // 4 KB
    __shared__ float sV[HD * HD];         // 4 KB
    __shared__ float sQ[TT * HD * HD];    // 12 KB
    __shared__ float sRW[TT * HD * HD];   // 12 KB
    __shared__ float sh[8 * HD];          // 1 KB
    __shared__ float sv[8 * HD];          // 1 KB
    const float* wk = Wk + layer * HD * HD;
    const float* wv = Wv + layer * HD * HD;
    for (int i = threadIdx.x; i < HD * HD; i += 256) { sK[i] = wk[i]; sV[i] = wv[i]; }
    for (int i = threadIdx.x; i < TT * HD * HD; i += 256) { sQ[i] = WqR[i]; sRW[i] = RW[i]; }
    int node0 = blockIdx.x * 8;
    {
        const float4* hs = (const float4*)(h + (size_t)node0 * HD);
        float4* dst4 = (float4*)sh;
        if (threadIdx.x < 64) dst4[threadIdx.x] = hs[threadIdx.x];
    }
    __syncthreads();
    int ln = threadIdx.x / HD, d = threadIdx.x % HD;
    int n = node0 + ln;
    float ak = 0.f, av = 0.f, a0 = 0.f, a1 = 0.f, a2 = 0.f;
    #pragma unroll
    for (int i = 0; i < HD; ++i) {
        float hv = sh[ln * HD + i];
        ak += hv * sK[i * HD + d];
        av += hv * sV[i * HD + d];
        a0 += hv * sQ[0 * HD * HD + i * HD + d];
        a1 += hv * sQ[1 * HD * HD + i * HD + d];
        a2 += hv * sQ[2 * HD * HD + i * HD + d];
    }
    k16[(size_t)n * HD + d] = __float2half(ak);
    q16[(0 * (size_t)NN + n) * HD + d] = __float2half(a0);
    q16[(1 * (size_t)NN + n) * HD + d] = __float2half(a1);
    q16[(2 * (size_t)NN + n) * HD + d] = __float2half(a2);
    sv[ln * HD + d] = av;
    __syncthreads();
    float w0 = 0.f, w1 = 0.f, w2 = 0.f;
    #pragma unroll
    for (int j = 0; j < HD; ++j) {
        float vv = sv[ln * HD + j];
        w0 += vv * sRW[0 * HD * HD + j * HD + d];
        w1 += vv * sRW[1 * HD * HD + j * HD + d];
        w2 += vv * sRW[2 * HD * HD + j * HD + d];
    }
    vrw16[(0 * (size_t)NN + n) * HD + d] = __float2half(w0);
    vrw16[(1 * (size_t)NN + n) * HD + d] = __float2half(w1);
    vrw16[(2 * (size_t)NN + n) * HD + d] = __float2half(w2);
}

__device__ __forceinline__ float dot4_h(float2 kraw, float2 qraw) {
    __half2 k01 = *(__half2*)&kraw.x, k23 = *(__half2*)&kraw.y;
    __half2 q01 = *(__half2*)&qraw.x, q23 = *(__half2*)&qraw.y;
    float2 a = __half22float2(k01), b = __half22float2(q01);
    float2 c = __half22float2(k23), e = __half22float2(q23);
    return a.x * b.x + a.y * b.y + c.x * e.x + c.y * e.y;
}

// logits in CSR slot order; payload {x=exp(a), row = t*NN+src}.
// Shift-0 softmax is exact here: |logit| <= ~0.5 given 0.05-scaled weights.
__global__ void edge_logits_exp(const int* __restrict__ einfo, const int* __restrict__ dcsr,
                                const __half* __restrict__ k16, const __half* __restrict__ q16,
                                float2* __restrict__ pay) {
    int p = blockIdx.x * 32 + (threadIdx.x >> 3);
    if (p >= NE) return;
    int g = threadIdx.x & 7;
    int sid = einfo[p];
    unsigned srcn = ((unsigned)sid) >> 2, t = (unsigned)sid & 3;
    int dn = dcsr[p];
    float2 kraw = ((const float2*)k16)[(size_t)srcn * 8 + g];
    float2 qraw = ((const float2*)q16)[((size_t)t * NN + dn) * 8 + g];
    float acc = dot4_h(kraw, qraw);
    acc += __shfl_xor(acc, 1);
    acc += __shfl_xor(acc, 2);
    acc += __shfl_xor(acc, 4);
    if (g == 0) {
        unsigned y = t * NN + srcn;     // row into vrw16
        pay[p] = make_float2(__expf(acc), __uint_as_float(y));
    }
}

// one wave per node: 4 slot-groups x 16 lanes (half2 per lane = 2 dims).
// o[d] = sum_slots x * vrw[row][d]; den = sum x; then gate+relu store.
// No LDS, no barrier, no per-node matmul (folded into vrw).
__global__ __launch_bounds__(256) void node_agg_out7(
        const int* __restrict__ rowptr, const float2* __restrict__ pay,
        const __half* __restrict__ vrw16, const float* __restrict__ skip,
        float* __restrict__ h, int layer) {
    int lane = threadIdx.x & 63;
    int wid = threadIdx.x >> 6;           // 0..3
    int n = blockIdx.x * 4 + wid;
    int g = lane >> 4;                    // slot group 0..3
    int ld = lane & 15;                   // dim pair 0..15
    int sb = (n >> BSH) * NSEG + (n & 511) * TT;
    int b0 = rowptr[sb], b3 = rowptr[sb + TT];
    float ox = 0.f, oy = 0.f, den = 0.f;
    const __half2* vr2 = (const __half2*)vrw16;
    for (int c = b0 + g; c < b3; c += 4) {
        float2 pp = pay[c];
        unsigned y = __float_as_uint(pp.y);
        float x = pp.x;
        __half2 hv = vr2[(size_t)y * 16 + ld];
        float2 f = __half22float2(hv);
        ox += x * f.x;
        oy += x * f.y;
        den += x;
    }
    ox += __shfl_xor(ox, 16); oy += __shfl_xor(oy, 16); den += __shfl_xor(den, 16);
    ox += __shfl_xor(ox, 32); oy += __shfl_xor(oy, 32); den += __shfl_xor(den, 32);
    if (lane < 16) {
        float inv = (b3 > b0) ? 1.f / den : 0.f;
        float gate = 1.f / (1.f + __expf(-skip[layer]));
        size_t idx = (size_t)n * HD + 2 * ld;
        float2 hh = *(float2*)&h[idx];
        float2 res;
        res.x = fmaxf(ox * inv * gate + hh.x * (1.f - gate), 0.f);
        res.y = fmaxf(oy * inv * gate + hh.y * (1.f - gate), 0.f);
        *(float2*)&h[idx] = res;
    }
}

// out = h @ mlp_W + mlp_b  (C=2)
__global__ void mlp_out(const float* __restrict__ h, const float* __restrict__ W,
                        const float* __restrict__ b, float* __restrict__ out) {
    int n = blockIdx.x * blockDim.x + threadIdx.x;
    if (n >= NN) return;
    const float4* hr = (const float4*)(h + (size_t)n * HD);
    float acc0 = b[0], acc1 = b[1];
    #pragma unroll
    for (int j = 0; j < HD / 4; ++j) {
        float4 hv = hr[j];
        acc0 += hv.x * W[(4 * j + 0) * 2 + 0] + hv.y * W[(4 * j + 1) * 2 + 0]
              + hv.z * W[(4 * j + 2) * 2 + 0] + hv.w * W[(4 * j + 3) * 2 + 0];
        acc1 += hv.x * W[(4 * j + 0) * 2 + 1] + hv.y * W[(4 * j + 1) * 2 + 1]
              + hv.z * W[(4 * j + 2) * 2 + 1] + hv.w * W[(4 * j + 3) * 2 + 1];
    }
    out[(size_t)n * 2 + 0] = acc0;
    out[(size_t)n * 2 + 1] = acc1;
}

extern "C" void kernel_launch(void* const* d_in, const int* in_sizes, int n_in,
                              void* d_out, int out_size, void* d_ws, size_t ws_size,
                              hipStream_t stream) {
    const float* x     = (const float*)d_in[0];
    const int*   src   = (const int*)d_in[1];
    const int*   dst   = (const int*)d_in[2];
    const int*   etype = (const int*)d_in[3];
    const float* in_W  = (const float*)d_in[4];
    const float* in_b  = (const float*)d_in[5];
    const float* Wk    = (const float*)d_in[6];
    const float* Wq    = (const float*)d_in[7];
    const float* Wv    = (const float*)d_in[8];
    const float* Wa    = (const float*)d_in[9];
    const float* pri   = (const float*)d_in[10];
    const float* Ratt  = (const float*)d_in[11];
    const float* Rmsg  = (const float*)d_in[12];
    const float* skip  = (const float*)d_in[13];
    const float* mlp_W = (const float*)d_in[14];
    const float* mlp_b = (const float*)d_in[15];
    float* out = (float*)d_out;

    float* ws = (float*)d_ws;
    float*  h     = ws;                            // NN*HD f32
    float2* pay   = (float2*)(h + (size_t)NN * HD);// NE float2
    float*  WqR   = (float*)(pay + NE);            // 3*HD*HD f32
    float*  RW    = WqR + TT * HD * HD;            // 3*HD*HD f32
    __half* k16   = (__half*)(RW + TT * HD * HD);  // NN*HD halves
    __half* q16   = k16 + (size_t)NN * HD;         // 3*NN*HD halves
    __half* vrw16 = q16 + (size_t)3 * NN * HD;     // 3*NN*HD halves
    int* rowptr   = (int*)(vrw16 + (size_t)3 * NN * HD);  // NBUK*NSEG + 1
    int* cursor   = rowptr + NBUK * NSEG + 1;      // 256
    int* bbase    = cursor + 256;                  // 256
    int* einfo    = bbase + 256;                   // NE
    int* dcsr     = einfo + NE;                    // NE
    unsigned* bin = (unsigned*)(dcsr + NE);        // NBUK*BCAP

    input_proj<<<NN / 8, 256, 0, stream>>>(x, in_W, in_b, h);

    zero_cursor<<<1, 256, 0, stream>>>(cursor);
    bin_edges<<<NCHNK, 256, 0, stream>>>(src, dst, etype, bin, cursor);
    scan_buckets<<<1, 256, 0, stream>>>(cursor, bbase);
    build_bucket<<<NBUK, 256, 0, stream>>>(bin, cursor, bbase, rowptr, einfo, dcsr);

    for (int l = 0; l < LL; ++l) {
        combine_mats2<<<(2 * TT * HD * HD + 255) / 256, 256, 0, stream>>>(
            Wq, Ratt, Rmsg, Wa, pri, WqR, RW, l);
        node_proj7<<<NN / 8, 256, 0, stream>>>(h, Wk, Wv, WqR, RW, k16, q16, vrw16, l);
        edge_logits_exp<<<(NE + 31) / 32, 256, 0, stream>>>(einfo, dcsr, k16, q16, pay);
        node_agg_out7<<<NN / 4, 256, 0, stream>>>(rowptr, pay, vrw16, skip, h, l);
    }
    mlp_out<<<(NN + 255) / 256, 256, 0, stream>>>(h, mlp_W, mlp_b, out);
}